// Round 5
// baseline (6629.010 us; speedup 1.0000x reference)
//
#include <hip/hip_runtime.h>
#include <math.h>

#define B_ 8
#define S_ 2048
#define E_ 1024
#define H_ 1024
#define M_ 16384   // B_*S_

typedef __attribute__((ext_vector_type(8))) short short8;    // 8 bf16 = 4 VGPRs
typedef __attribute__((ext_vector_type(4))) float floatx4;

// ---------------- block-wide reduction of two floats (256 threads = 4 waves) ----------------
__device__ __forceinline__ void block_reduce2(float &a, float &b) {
#pragma unroll
  for (int off = 32; off > 0; off >>= 1) {
    a += __shfl_down(a, off);
    b += __shfl_down(b, off);
  }
  __shared__ float sa[4], sb[4];
  const int w = threadIdx.x >> 6;
  __syncthreads();                 // protects reuse across back-to-back calls
  if ((threadIdx.x & 63) == 0) { sa[w] = a; sb[w] = b; }
  __syncthreads();
  a = sa[0] + sa[1] + sa[2] + sa[3];
  b = sb[0] + sb[1] + sb[2] + sb[3];
}

// ---------------- LayerNorm(x) -> x_norm, plus delta = softplus(x_norm . delta_w + delta_b) ----------------
__global__ __launch_bounds__(256) void ln_delta_kernel(
    const float* __restrict__ x, const float* __restrict__ g, const float* __restrict__ bt,
    const float* __restrict__ dw, const float* __restrict__ db,
    float* __restrict__ xn, float* __restrict__ delta)
{
  const int row = blockIdx.x;
  const int t = threadIdx.x;
  const float4 v = ((const float4*)(x + (size_t)row * E_))[t];
  float s1 = v.x + v.y + v.z + v.w;
  float s2 = v.x*v.x + v.y*v.y + v.z*v.z + v.w*v.w;
  block_reduce2(s1, s2);
  const float mean = s1 * (1.f / E_);
  const float var  = s2 * (1.f / E_) - mean * mean;
  const float rstd = rsqrtf(var + 1e-5f);
  const float4 g4 = ((const float4*)g)[t];
  const float4 b4 = ((const float4*)bt)[t];
  float4 o;
  o.x = (v.x - mean) * rstd * g4.x + b4.x;
  o.y = (v.y - mean) * rstd * g4.y + b4.y;
  o.z = (v.z - mean) * rstd * g4.z + b4.z;
  o.w = (v.w - mean) * rstd * g4.w + b4.w;
  ((float4*)(xn + (size_t)row * E_))[t] = o;
  const float4 d4 = ((const float4*)dw)[t];
  float dd = o.x*d4.x + o.y*d4.y + o.z*d4.z + o.w*d4.w;
  float dummy = 0.f;
  block_reduce2(dd, dummy);
  if (t == 0) {
    const float z = dd + db[0];
    delta[row] = (z > 20.f) ? z : log1pf(__expf(z));
  }
}

// ---------------- per-row mean/rstd of reservoir states (for fused ro-layernorm) ----------------
__global__ __launch_bounds__(256) void rowstats_kernel(
    const float* __restrict__ res, float2* __restrict__ st)
{
  const int row = blockIdx.x;
  const int t = threadIdx.x;
  const float4 v = ((const float4*)(res + (size_t)row * H_))[t];
  float s1 = v.x + v.y + v.z + v.w;
  float s2 = v.x*v.x + v.y*v.y + v.z*v.z + v.w*v.w;
  block_reduce2(s1, s2);
  if (t == 0) {
    const float m = s1 * (1.f / H_);
    const float var = s2 * (1.f / H_) - m * m;
    st[row] = make_float2(m, rsqrtf(var + 1e-5f));
  }
}

// ---------------- bf16 MFMA GEMM: C[M,N] = act(A[M,1024] @ W[N,1024]^T + bias) ----------------
__device__ __forceinline__ unsigned pack_bf16(float lo, float hi) {
  return __builtin_amdgcn_perm(__float_as_uint(hi) + 0x8000u,
                               __float_as_uint(lo) + 0x8000u, 0x07060302u);
}
// pack the hi16 of two u32 bit patterns: (hi16(a) in low half, hi16(b) in high half)
__device__ __forceinline__ unsigned pack_hi16(unsigned a, unsigned b) {
  return __builtin_amdgcn_perm(b, a, 0x07060302u);
}

template<int ACT>
__global__ __launch_bounds__(256) void gemm_bf16_nt(
    const float* __restrict__ A, const float* __restrict__ W,
    const float* __restrict__ bias, float* __restrict__ C)
{
  __shared__ __align__(16) unsigned short As[128 * 40];
  __shared__ __align__(16) unsigned short Ws[128 * 40];
  const int tid  = threadIdx.x;
  const int bn   = blockIdx.x & 7;
  const int bm   = blockIdx.x >> 3;
  const int wave = tid >> 6, lane = tid & 63;
  const int wm = (wave >> 1) * 64, wn = (wave & 1) * 64;
  const int fm = lane & 15, quad = lane >> 4;

  floatx4 acc[4][4];
#pragma unroll
  for (int i = 0; i < 4; ++i)
#pragma unroll
    for (int j = 0; j < 4; ++j) acc[i][j] = (floatx4){0.f, 0.f, 0.f, 0.f};

  const float* Abase = A + (size_t)bm * 128 * 1024;
  const float* Wbase = W + (size_t)bn * 128 * 1024;

  for (int k0 = 0; k0 < 1024; k0 += 32) {
    float4 a4[4], w4[4];
#pragma unroll
    for (int i = 0; i < 4; ++i) {
      const int q = tid + 256 * i;
      const int row = q >> 3, ch = q & 7;
      a4[i] = *(const float4*)(Abase + (size_t)row * 1024 + k0 + ch * 4);
      w4[i] = *(const float4*)(Wbase + (size_t)row * 1024 + k0 + ch * 4);
    }
#pragma unroll
    for (int i = 0; i < 4; ++i) {
      const int q = tid + 256 * i;
      const int row = q >> 3, ch = q & 7;
      uint2 pa, pw;
      pa.x = pack_bf16(a4[i].x, a4[i].y); pa.y = pack_bf16(a4[i].z, a4[i].w);
      pw.x = pack_bf16(w4[i].x, w4[i].y); pw.y = pack_bf16(w4[i].z, w4[i].w);
      *(uint2*)(&As[row * 40 + ch * 4]) = pa;
      *(uint2*)(&Ws[row * 40 + ch * 4]) = pw;
    }
    __syncthreads();
    short8 af[4], wf[4];
#pragma unroll
    for (int i = 0; i < 4; ++i) {
      af[i] = *(const short8*)(&As[(wm + i * 16 + fm) * 40 + quad * 8]);
      wf[i] = *(const short8*)(&Ws[(wn + i * 16 + fm) * 40 + quad * 8]);
    }
#pragma unroll
    for (int i = 0; i < 4; ++i)
#pragma unroll
      for (int j = 0; j < 4; ++j)
        acc[i][j] = __builtin_amdgcn_mfma_f32_16x16x32_bf16(af[i], wf[j], acc[i][j], 0, 0, 0);
    __syncthreads();
  }

  // epilogue: C/D layout col=lane&15, row=quad*4+reg (m89/m91)
#pragma unroll
  for (int i = 0; i < 4; ++i) {
    const int grow0 = bm * 128 + wm + i * 16 + quad * 4;
#pragma unroll
    for (int j = 0; j < 4; ++j) {
      const int gcol = bn * 128 + wn + j * 16 + fm;
      const float bb = (ACT == 1) ? bias[gcol] : 0.f;
#pragma unroll
      for (int r = 0; r < 4; ++r) {
        float v = acc[i][j][r] + bb;
        if (ACT == 1) v = 1.f / (1.f + __expf(-v));
        C[(size_t)(grow0 + r) * 1024 + gcol] = v;
      }
    }
  }
}

// ---------------- readout GEMM, MFMA hi/lo version ----------------
// out[gr,e] = blend(gelu(LN(res)[gr,:] . ro_w[e,:] + bias[e]), ssm_recon, gate)
// fp32-equivalent accuracy via hi/lo bf16 split of BOTH operands, 3 MFMA products:
//   A*W ~= Ah*Wh + Al*Wh + Ah*Wl   (dropped Al*Wl term ~2^-17 relative)
// LN fused into A-staging; epilogue = gelu + ssm reconstruction + gate blend (ported).
__global__ __launch_bounds__(256) void gemm_readout_mfma(
    const float* __restrict__ A,      // reservoir states [M,1024]
    const float* __restrict__ W,      // ro_w [1024,1024] (row e, col h)
    const float* __restrict__ bias,   // ro_bias
    const float2* __restrict__ lnst,  // per-row mean/rstd
    const float* __restrict__ lng, const float* __restrict__ lnb,
    const float* __restrict__ Avec,   // A[h]
    const float* __restrict__ cumd,   // within-chunk cumulative delta [M]
    const float* __restrict__ chH,    // per-chunk initial ssm state [B,16,1024]
    const float* __restrict__ gate,   // [M,1024]
    float* __restrict__ C)            // d_out: in = ssm local states, out = final
{
  __shared__ __align__(16) unsigned short Ah[128 * 40];
  __shared__ __align__(16) unsigned short Al[128 * 40];
  __shared__ __align__(16) unsigned short Wh[128 * 40];
  __shared__ __align__(16) unsigned short Wl[128 * 40];
  const int tid  = threadIdx.x;
  const int bn   = blockIdx.x & 7;
  const int bm   = blockIdx.x >> 3;
  const int wave = tid >> 6, lane = tid & 63;
  const int wm = (wave >> 1) * 64, wn = (wave & 1) * 64;
  const int fm = lane & 15, quad = lane >> 4;

  floatx4 acc[4][4];
#pragma unroll
  for (int i = 0; i < 4; ++i)
#pragma unroll
    for (int j = 0; j < 4; ++j) acc[i][j] = (floatx4){0.f, 0.f, 0.f, 0.f};

  const float* Abase = A + (size_t)bm * 128 * 1024;
  const float* Wbase = W + (size_t)bn * 128 * 1024;

  // per-thread staged-row stats (row fixed per i across k-tiles)
  float2 st_i[4];
#pragma unroll
  for (int i = 0; i < 4; ++i) {
    const int q = tid + 256 * i;
    st_i[i] = lnst[bm * 128 + (q >> 3)];
  }

  for (int k0 = 0; k0 < 1024; k0 += 32) {
#pragma unroll
    for (int i = 0; i < 4; ++i) {
      const int q = tid + 256 * i;
      const int row = q >> 3, ch = q & 7;
      float4 a4 = *(const float4*)(Abase + (size_t)row * 1024 + k0 + ch * 4);
      const float4 w4 = *(const float4*)(Wbase + (size_t)row * 1024 + k0 + ch * 4);
      const float4 g4 = *(const float4*)(lng + k0 + ch * 4);
      const float4 b4 = *(const float4*)(lnb + k0 + ch * 4);
      const float2 st = st_i[i];
      a4.x = (a4.x - st.x) * st.y * g4.x + b4.x;
      a4.y = (a4.y - st.x) * st.y * g4.y + b4.y;
      a4.z = (a4.z - st.x) * st.y * g4.z + b4.z;
      a4.w = (a4.w - st.x) * st.y * g4.w + b4.w;
      // hi/lo split of A
      const float av[4] = {a4.x, a4.y, a4.z, a4.w};
      const float wv[4] = {w4.x, w4.y, w4.z, w4.w};
      unsigned ah[4], wh[4];
      float alr[4], wlr[4];
#pragma unroll
      for (int e = 0; e < 4; ++e) {
        ah[e] = (__float_as_uint(av[e]) + 0x8000u) & 0xFFFF0000u;
        alr[e] = av[e] - __uint_as_float(ah[e]);
        wh[e] = (__float_as_uint(wv[e]) + 0x8000u) & 0xFFFF0000u;
        wlr[e] = wv[e] - __uint_as_float(wh[e]);
      }
      uint2 pah, pal, pwh, pwl;
      pah.x = pack_hi16(ah[0], ah[1]); pah.y = pack_hi16(ah[2], ah[3]);
      pwh.x = pack_hi16(wh[0], wh[1]); pwh.y = pack_hi16(wh[2], wh[3]);
      pal.x = pack_bf16(alr[0], alr[1]); pal.y = pack_bf16(alr[2], alr[3]);
      pwl.x = pack_bf16(wlr[0], wlr[1]); pwl.y = pack_bf16(wlr[2], wlr[3]);
      *(uint2*)(&Ah[row * 40 + ch * 4]) = pah;
      *(uint2*)(&Al[row * 40 + ch * 4]) = pal;
      *(uint2*)(&Wh[row * 40 + ch * 4]) = pwh;
      *(uint2*)(&Wl[row * 40 + ch * 4]) = pwl;
    }
    __syncthreads();
    short8 afh[4], afl[4], wfh[4], wfl[4];
#pragma unroll
    for (int i = 0; i < 4; ++i) {
      const int ao = (wm + i * 16 + fm) * 40 + quad * 8;
      const int wo = (wn + i * 16 + fm) * 40 + quad * 8;
      afh[i] = *(const short8*)(&Ah[ao]);
      afl[i] = *(const short8*)(&Al[ao]);
      wfh[i] = *(const short8*)(&Wh[wo]);
      wfl[i] = *(const short8*)(&Wl[wo]);
    }
#pragma unroll
    for (int i = 0; i < 4; ++i)
#pragma unroll
      for (int j = 0; j < 4; ++j) {
        acc[i][j] = __builtin_amdgcn_mfma_f32_16x16x32_bf16(afh[i], wfh[j], acc[i][j], 0, 0, 0);
        acc[i][j] = __builtin_amdgcn_mfma_f32_16x16x32_bf16(afl[i], wfh[j], acc[i][j], 0, 0, 0);
        acc[i][j] = __builtin_amdgcn_mfma_f32_16x16x32_bf16(afh[i], wfl[j], acc[i][j], 0, 0, 0);
      }
    __syncthreads();
  }

  // epilogue: C/D layout col=lane&15, row=quad*4+reg; gelu + ssm recon + gate blend
#pragma unroll
  for (int i = 0; i < 4; ++i) {
    const int grow0 = bm * 128 + wm + i * 16 + quad * 4;
    float cd_r[4];
    int hb_r[4];
#pragma unroll
    for (int r = 0; r < 4; ++r) {
      const int gr = grow0 + r;
      const int b = gr >> 11;           // gr = b*2048 + s
      const int c = (gr & 2047) >> 7;   // 128-step chunk
      cd_r[r] = cumd[gr];
      hb_r[r] = (b * 16 + c) << 10;
    }
#pragma unroll
    for (int j = 0; j < 4; ++j) {
      const int gcol = bn * 128 + wn + j * 16 + fm;
      const float Ae = Avec[gcol];
      const float bb = bias[gcol];
#pragma unroll
      for (int r = 0; r < 4; ++r) {
        const int gr = grow0 + r;
        const size_t off = (size_t)gr * 1024 + gcol;
        const float hin = chH[hb_r[r] + gcol];
        const float lcl = C[off];
        const float gt  = gate[off];
        float v = acc[i][j][r] + bb;
        v = 0.5f * v * (1.f + erff(v * 0.70710678118654752f));   // exact gelu
        const float p = __expf(Ae * cd_r[r]);                    // prod of A_bar over chunk prefix
        const float sst = lcl + p * hin;                         // true ssm state
        C[off] = v * gt + sst * (1.f - gt);
      }
    }
  }
}

// ---------------- reservoir scan: persistent 16-WG x 512-thread kernel ----------------
// Exchange protocol identical (self-certifying words bf16(h)<<16|tag, relaxed AGENT-scope
// atomics, global parity buffers, zeroed before launch). v5: ONE barrier per step.
//   * Each wave owns 8 real rows x FULL K=1024. A-frag packs W_hi of rows 0..7 into
//     fragment rows 0..7 and W_lo of the SAME rows into fragment rows 8..15 -> one MFMA
//     produces hi-partials (C rows 0..7) and lo-partials (C rows 8..15) together.
//   * hi+lo combine = __shfl_xor(csum, 32) (C-quad q <-> q+2 lives at lane+-32): intra-wave,
//     no LDS round trip, no second barrier. red[] tile deleted.
//   * Active lanes (quad<2, fm<8) own 4 CONSECUTIVE rows: u-load = one float4,
//     xin-store = one float4, handoff = two u64 atomic stores.
//   * W frags: 32 x short8 = 128 VGPR (same budget as v4's hi/lo K-half split).
// Safety: a thread stores tag s+1 only after barrier#1(s), which post-dates ALL its WG's
// tag-s polls; a WG stores tag s+2 (overwriting parity buffer s) only after poll(s+1)
// success, certifying every WG passed barrier#1(s), i.e. finished staging AND will not
// re-read buffer s (its LDS copy is private). LDS dbuf reuse: stage(s+2) into hbf[s&1]
// post-dates barrier#1(s+1), which post-dates every wave's MFMA reads(s) in program order.
__global__ __launch_bounds__(512, 2) void reservoir_scan_kernel(
    float* __restrict__ xin_res,       // [8][2048][1024]: in xin, out res states (in-place)
    const float* __restrict__ Wres,    // [1024][1024]
    unsigned* __restrict__ hbuf,       // [2][8192] packed words, zeroed before launch
    unsigned* __restrict__ unused)
{
  const int tid  = threadIdx.x;
  const int wg   = blockIdx.x;         // 0..15
  const int g    = tid >> 6;           // wave 0..7
  const int lane = tid & 63;
  const int fm   = lane & 15;          // MFMA m (A row) / n (C col)
  const int quad = lane >> 4;          // MFMA k-quad
  const int rfm  = fm & 7;             // real row within the wave's 8-row group
  const int row8 = wg * 64 + g * 8;    // wave's 8-row base

  __shared__ __align__(16) unsigned short hbf[2][8 * 1040];  // dbuf bf16 h, padded batch stride

  // ---- W fragments: rows fm<8 = bf16_hi(W[row8+fm]), fm>=8 = bf16_lo(W[row8+fm-8]) ----
  short8 wf[32];
  {
    const float* wrow = Wres + (size_t)(row8 + rfm) * 1024 + quad * 8;
    const bool lo = (fm >= 8);
#pragma unroll
    for (int k0 = 0; k0 < 32; ++k0) {
      const float4 wa = *(const float4*)(wrow + k0 * 32);
      const float4 wb = *(const float4*)(wrow + k0 * 32 + 4);
      const float wv[8] = {wa.x, wa.y, wa.z, wa.w, wb.x, wb.y, wb.z, wb.w};
      short8 f8;
#pragma unroll
      for (int j = 0; j < 8; ++j) {
        const unsigned bits = __float_as_uint(wv[j]);
        const unsigned hb   = (bits + 0x8000u) & 0xFFFF0000u;
        if (lo) {
          const float l = wv[j] - __uint_as_float(hb);
          f8[j] = (short)((__float_as_uint(l) + 0x8000u) >> 16);
        } else {
          f8[j] = (short)(hb >> 16);
        }
      }
      wf[k0] = f8;
    }
  }

  const int  bb    = fm & 7;           // B-frag batch (C cols 8..15 duplicate, discarded)
  const bool act   = (quad < 2) && (fm < 8);   // output-owning lanes
  const int  jrow4 = row8 + quad * 4;  // first of this lane's 4 consecutive rows (when act)
  float4 hprev = {0.f, 0.f, 0.f, 0.f};

  const int xw = tid >> 2;             // staging: k-block of this thread's pair (k = 2*tid)
  const int ow = (tid & 3) * 2;        // offset within 8-short block

  for (int s = 0; s < S_; ++s) {
    // ---- prefetch u before the poll (keep-alive pins issue order) ----
    float4 u4 = {0.f, 0.f, 0.f, 0.f};
    if (act) {
      u4 = *(const float4*)(xin_res + ((size_t)bb * S_ + s) * H_ + jrow4);
      asm volatile("" :: "v"(u4.x), "v"(u4.y), "v"(u4.z), "v"(u4.w));
    }

    // ---- poll+load h^s: 8x u64 coalesced; both 16-bit tags must equal s ----
    const unsigned tag = (unsigned)s & 0xFFFFu;
    const unsigned long long tag2 = (unsigned long long)tag | ((unsigned long long)tag << 32);
    const unsigned long long* hp8 =
        (const unsigned long long*)(hbuf + (size_t)(s & 1) * 8192) + tid;  // pair idx tid+512*i
    unsigned long long w8[8];
    for (;;) {
      bool ok = true;
#pragma unroll
      for (int i = 0; i < 8; ++i)
        w8[i] = __hip_atomic_load(hp8 + 512 * i, __ATOMIC_RELAXED, __HIP_MEMORY_SCOPE_AGENT);
#pragma unroll
      for (int i = 0; i < 8; ++i)
        ok &= (((w8[i] ^ tag2) & 0x0000FFFF0000FFFFull) == 0ull);
      if (ok) break;
    }

    // ---- stage h^s to LDS buffer s&1: pair (k=2*tid, 2*tid+1) for each batch ----
    {
      unsigned short* hb = &hbf[s & 1][0];
#pragma unroll
      for (int b = 0; b < 8; ++b) {
        const unsigned lo = (unsigned)(w8[b]);
        const unsigned hi = (unsigned)(w8[b] >> 32);
        const unsigned pk = __builtin_amdgcn_perm(hi, lo, 0x07060302u);  // (bf16 k, bf16 k+1)
        *(unsigned*)(hb + b * 1040 + ((xw ^ b) << 3) + ow) = pk;
      }
    }
    __syncthreads();                   // barrier#1 (the only one): staged; all polls done
                                       // before any tag-s+1 store below (safety inv.)

    // ---- MFMA matvec: 8 real rows (hi+lo packed) x 8 batches over FULL K=1024 ----
    const unsigned short* hrow = &hbf[s & 1][bb * 1040];
    floatx4 acc[8];
#pragma unroll
    for (int i = 0; i < 8; ++i) acc[i] = (floatx4){0.f, 0.f, 0.f, 0.f};
#pragma unroll
    for (int k0 = 0; k0 < 32; ++k0) {
      const int X = k0 * 4 + quad;     // global 8-block index of this k-frag
      const short8 hb8 = *(const short8*)(hrow + ((X ^ bb) << 3));
      acc[k0 & 7] = __builtin_amdgcn_mfma_f32_16x16x32_bf16(wf[k0], hb8, acc[k0 & 7], 0, 0, 0);
    }
    // C layout: col=lane&15, row=quad*4+r. Rows 0..7 = hi partials, rows 8..15 = lo
    // partials of the SAME real rows -> combine across lane+-32 (quad q <-> q+2).
    floatx4 csum;
#pragma unroll
    for (int r = 0; r < 4; ++r)
      csum[r] = ((acc[0][r] + acc[1][r]) + (acc[2][r] + acc[3][r]))
              + ((acc[4][r] + acc[5][r]) + (acc[6][r] + acc[7][r]));
    float dot[4];
#pragma unroll
    for (int r = 0; r < 4; ++r)
      dot[r] = csum[r] + __shfl_xor(csum[r], 32);   // all lanes participate

    // ---- tail (active lanes): tanh, leak, handoff stores first, then fp32 states ----
    if (act) {
      const unsigned tag1 = (unsigned)(s + 1) & 0xFFFFu;
      unsigned wv4[4];
      float4 hv4;
      float* ph = &hv4.x;
      float* pp = &hprev.x;
      const float* pu = &u4.x;
#pragma unroll
      for (int r = 0; r < 4; ++r) {
        const float z  = pu[r] + dot[r];
        const float e  = __expf(2.f * z);                 // tanh(z) = 1 - 2/(e^{2z}+1)
        const float hn = 1.f - __fdividef(2.f, e + 1.f);  // saturates correctly
        const float hv = 0.95f * hn + 0.05f * pp[r];
        pp[r] = hv;
        ph[r] = hv;
        wv4[r] = ((__float_as_uint(hv) + 0x8000u) & 0xFFFF0000u) | tag1;
      }
      unsigned* op = hbuf + (size_t)((s + 1) & 1) * 8192 + (size_t)bb * 1024 + jrow4;
      const unsigned long long p01 = (unsigned long long)wv4[0] | ((unsigned long long)wv4[1] << 32);
      const unsigned long long p23 = (unsigned long long)wv4[2] | ((unsigned long long)wv4[3] << 32);
      __hip_atomic_store((unsigned long long*)op,       p01, __ATOMIC_RELAXED, __HIP_MEMORY_SCOPE_AGENT);
      __hip_atomic_store((unsigned long long*)(op + 2), p23, __ATOMIC_RELAXED, __HIP_MEMORY_SCOPE_AGENT);
      *(float4*)(xin_res + ((size_t)bb * S_ + s) * H_ + jrow4) = hv4;  // fp32 to readout path
    }
    // no drain, no flag, no rendezvous — next iteration's poll is the wait
  }
}

// ---------------- SSM chunked scan ----------------
// within-chunk cumulative delta (tiny)
__global__ __launch_bounds__(128) void cumd_kernel(
    const float* __restrict__ delta, float* __restrict__ cumd)
{
  const int t = threadIdx.x;          // 128 = 8 batches * 16 chunks
  const int b = t >> 4, c = t & 15;
  const int base = b * S_ + c * 128;
  float acc = 0.f;
  for (int i = 0; i < 128; ++i) { acc += delta[base + i]; cumd[base + i] = acc; }
}

// phase A: per-chunk local scan, in-place Bx -> local states; store chunk products
__global__ __launch_bounds__(256) void ssm_partial_kernel(
    const float* __restrict__ delta, const float* __restrict__ Avec,
    float* __restrict__ bx, float* __restrict__ P)
{
  const int idx = blockIdx.x * 256 + threadIdx.x;
  const int h = idx & 1023;
  const int c = (idx >> 10) & 15;
  const int b = idx >> 14;
  const float Ah = Avec[h];
  const float inv = 1.f / (Ah + 1e-8f);
  const float* dp = delta + b * S_ + c * 128;
  float* xp = bx + ((size_t)(b * S_ + c * 128)) * H_ + h;
  float p = 1.f, hl = 0.f;
  for (int t = 0; t < 128; ++t) {
    const float a = __expf(Ah * dp[t]);
    const float bb = xp[(size_t)t * H_] * (1.f - a) * inv;
    hl = a * hl + bb;
    p *= a;
    xp[(size_t)t * H_] = hl;
  }
  P[(b * 16 + c) * 1024 + h] = p;
}

// phase B: sequential combine over 16 chunks -> per-chunk initial states
__global__ __launch_bounds__(256) void ssm_combine_kernel(
    const float* __restrict__ P, const float* __restrict__ local, float* __restrict__ Hin)
{
  const int idx = blockIdx.x * 256 + threadIdx.x;  // 8192
  const int h = idx & 1023;
  const int b = idx >> 10;
  float hh = 0.f;
#pragma unroll
  for (int c = 0; c < 16; ++c) {
    const int o = (b * 16 + c) * 1024 + h;
    Hin[o] = hh;
    hh = P[o] * hh + local[((size_t)(b * S_ + c * 128 + 127)) * H_ + h];
  }
}

// ---------------- host launch ----------------
extern "C" void kernel_launch(void* const* d_in, const int* in_sizes, int n_in,
                              void* d_out, int out_size, void* d_ws, size_t ws_size,
                              hipStream_t stream) {
  (void)in_sizes; (void)n_in; (void)out_size; (void)ws_size;
  const float* x      = (const float*)d_in[0];
  const float* W_in   = (const float*)d_in[1];
  const float* W_res  = (const float*)d_in[2];
  const float* norm_g = (const float*)d_in[3];
  const float* norm_b = (const float*)d_in[4];
  const float* dw     = (const float*)d_in[5];
  const float* db     = (const float*)d_in[6];
  const float* Avec   = (const float*)d_in[7];
  const float* B_w    = (const float*)d_in[8];
  const float* ro_g   = (const float*)d_in[9];
  const float* ro_b   = (const float*)d_in[10];
  const float* ro_w   = (const float*)d_in[11];
  const float* ro_bias= (const float*)d_in[12];
  const float* gate_w = (const float*)d_in[13];
  const float* gate_b = (const float*)d_in[14];
  float* out = (float*)d_out;
  float* ws  = (float*)d_ws;

  float*    buf0   = ws;                    // x_norm, later gate
  float*    buf1   = ws + 16777216;         // xin -> reservoir states (in-place)
  float*    delta  = ws + 33554432;         // [M]
  float*    cumd   = ws + 33570816;         // [M]
  unsigned* hbuf   = (unsigned*)(ws + 33587200);  // [2][8192] packed words
  float2*   stats  = (float2*)(ws + 33603712);
  float*    chP    = ws + 33636480;         // [B,16,1024]
  float*    chH    = ws + 33767552;         // [B,16,1024]

  // 1. layernorm + delta
  ln_delta_kernel<<<M_, 256, 0, stream>>>(x, norm_g, norm_b, dw, db, buf0, delta);
  // 2. xin = x_norm @ W_in^T   -> buf1   (bf16 MFMA)
  gemm_bf16_nt<0><<<1024, 256, 0, stream>>>(buf0, W_in, nullptr, buf1);
  // 3. Bx = x_norm @ B_w^T     -> d_out (scratch)   (bf16 MFMA)
  gemm_bf16_nt<0><<<1024, 256, 0, stream>>>(buf0, B_w, nullptr, out);
  // 4. gate = sigmoid(x @ gate_w^T + gate_b) -> buf0 (x_norm dead)   (bf16 MFMA)
  gemm_bf16_nt<1><<<1024, 256, 0, stream>>>(x, gate_w, gate_b, buf0);
  // 5. ssm chunked scan pieces (independent of reservoir)
  cumd_kernel<<<1, 128, 0, stream>>>(delta, cumd);
  ssm_partial_kernel<<<512, 256, 0, stream>>>(delta, Avec, out, chP);
  ssm_combine_kernel<<<32, 256, 0, stream>>>(chP, out, chH);
  // 6. reservoir scan (zero both parity buffers: word 0 == tag 0 | bf16(0))
  hipMemsetAsync(hbuf, 0, 2 * 8192 * sizeof(unsigned), stream);
  reservoir_scan_kernel<<<16, 512, 0, stream>>>(buf1, W_res, hbuf, nullptr);
  // 7. ro-layernorm stats
  rowstats_kernel<<<M_, 256, 0, stream>>>(buf1, stats);
  // 8. readout GEMM (MFMA hi/lo) + gelu + ssm reconstruction + gate blend -> d_out
  gemm_readout_mfma<<<1024, 256, 0, stream>>>(buf1, ro_w, ro_bias, stats, ro_g, ro_b,
                                              Avec, cumd, chH, buf0, out);
}

// Round 6
// 5056.138 us; speedup vs baseline: 1.3111x; 1.3111x over previous
//
#include <hip/hip_runtime.h>
#include <math.h>

#define B_ 8
#define S_ 2048
#define E_ 1024
#define H_ 1024
#define M_ 16384   // B_*S_

typedef __attribute__((ext_vector_type(8))) short short8;    // 8 bf16 = 4 VGPRs
typedef __attribute__((ext_vector_type(4))) float floatx4;

// ---------------- block-wide reduction of two floats (256 threads = 4 waves) ----------------
__device__ __forceinline__ void block_reduce2(float &a, float &b) {
#pragma unroll
  for (int off = 32; off > 0; off >>= 1) {
    a += __shfl_down(a, off);
    b += __shfl_down(b, off);
  }
  __shared__ float sa[4], sb[4];
  const int w = threadIdx.x >> 6;
  __syncthreads();                 // protects reuse across back-to-back calls
  if ((threadIdx.x & 63) == 0) { sa[w] = a; sb[w] = b; }
  __syncthreads();
  a = sa[0] + sa[1] + sa[2] + sa[3];
  b = sb[0] + sb[1] + sb[2] + sb[3];
}

__device__ __forceinline__ unsigned pack_bf16(float lo, float hi) {
  return __builtin_amdgcn_perm(__float_as_uint(hi) + 0x8000u,
                               __float_as_uint(lo) + 0x8000u, 0x07060302u);
}
// pack the hi16 of two u32 bit patterns: (hi16(a) in low half, hi16(b) in high half)
__device__ __forceinline__ unsigned pack_hi16(unsigned a, unsigned b) {
  return __builtin_amdgcn_perm(b, a, 0x07060302u);
}

// ---------------- LayerNorm(x) -> x_norm (bf16!), plus delta = softplus(x_norm . delta_w + db) ----------------
__global__ __launch_bounds__(256) void ln_delta_kernel(
    const float* __restrict__ x, const float* __restrict__ g, const float* __restrict__ bt,
    const float* __restrict__ dw, const float* __restrict__ db,
    unsigned short* __restrict__ xnb, float* __restrict__ delta)
{
  const int row = blockIdx.x;
  const int t = threadIdx.x;
  const float4 v = ((const float4*)(x + (size_t)row * E_))[t];
  float s1 = v.x + v.y + v.z + v.w;
  float s2 = v.x*v.x + v.y*v.y + v.z*v.z + v.w*v.w;
  block_reduce2(s1, s2);
  const float mean = s1 * (1.f / E_);
  const float var  = s2 * (1.f / E_) - mean * mean;
  const float rstd = rsqrtf(var + 1e-5f);
  const float4 g4 = ((const float4*)g)[t];
  const float4 b4 = ((const float4*)bt)[t];
  float4 o;
  o.x = (v.x - mean) * rstd * g4.x + b4.x;
  o.y = (v.y - mean) * rstd * g4.y + b4.y;
  o.z = (v.z - mean) * rstd * g4.z + b4.z;
  o.w = (v.w - mean) * rstd * g4.w + b4.w;
  uint2 p;
  p.x = pack_bf16(o.x, o.y); p.y = pack_bf16(o.z, o.w);
  ((uint2*)(xnb + (size_t)row * E_))[t] = p;       // bf16 x_norm (same rounding the GEMMs used)
  const float4 d4 = ((const float4*)dw)[t];
  float dd = o.x*d4.x + o.y*d4.y + o.z*d4.z + o.w*d4.w;   // delta stays fp32-accurate
  float dummy = 0.f;
  block_reduce2(dd, dummy);
  if (t == 0) {
    const float z = dd + db[0];
    delta[row] = (z > 20.f) ? z : log1pf(__expf(z));
  }
}

// ---------------- per-row mean/rstd of reservoir states (for fused ro-layernorm) ----------------
__global__ __launch_bounds__(256) void rowstats_kernel(
    const float* __restrict__ res, float2* __restrict__ st)
{
  const int row = blockIdx.x;
  const int t = threadIdx.x;
  const float4 v = ((const float4*)(res + (size_t)row * H_))[t];
  float s1 = v.x + v.y + v.z + v.w;
  float s2 = v.x*v.x + v.y*v.y + v.z*v.z + v.w*v.w;
  block_reduce2(s1, s2);
  if (t == 0) {
    const float m = s1 * (1.f / H_);
    const float var = s2 * (1.f / H_) - m * m;
    st[row] = make_float2(m, rsqrtf(var + 1e-5f));
  }
}

// ---------------- tiny converters (run once, off critical path) ----------------
__global__ __launch_bounds__(256) void tobf16_kernel(
    const float* __restrict__ s, unsigned short* __restrict__ d)
{
  const int i = blockIdx.x * 256 + threadIdx.x;
  const float4 v = ((const float4*)s)[i];
  uint2 p;
  p.x = pack_bf16(v.x, v.y); p.y = pack_bf16(v.z, v.w);
  ((uint2*)d)[i] = p;
}

__global__ __launch_bounds__(256) void splitw_kernel(
    const float* __restrict__ s, unsigned short* __restrict__ dh, unsigned short* __restrict__ dl)
{
  const int i = blockIdx.x * 256 + threadIdx.x;
  const float4 v = ((const float4*)s)[i];
  const float sv[4] = {v.x, v.y, v.z, v.w};
  unsigned h[4]; float l[4];
#pragma unroll
  for (int e = 0; e < 4; ++e) {
    h[e] = (__float_as_uint(sv[e]) + 0x8000u) & 0xFFFF0000u;
    l[e] = sv[e] - __uint_as_float(h[e]);
  }
  uint2 ph, pl;
  ph.x = pack_hi16(h[0], h[1]); ph.y = pack_hi16(h[2], h[3]);
  pl.x = pack_bf16(l[0], l[1]); pl.y = pack_bf16(l[2], l[3]);
  ((uint2*)dh)[i] = ph;
  ((uint2*)dl)[i] = pl;
}

// ---------------- bf16-input MFMA GEMM: C[M,N] = A[M,1024] @ W[N,1024]^T (A,W bf16) ----------------
__global__ __launch_bounds__(256) void gemm_bb(
    const unsigned short* __restrict__ A, const unsigned short* __restrict__ W,
    float* __restrict__ C)
{
  __shared__ __align__(16) unsigned short As[128 * 40];
  __shared__ __align__(16) unsigned short Ws[128 * 40];
  const int tid  = threadIdx.x;
  const int bn   = blockIdx.x & 7;
  const int bm   = blockIdx.x >> 3;
  const int wave = tid >> 6, lane = tid & 63;
  const int wm = (wave >> 1) * 64, wn = (wave & 1) * 64;
  const int fm = lane & 15, quad = lane >> 4;

  floatx4 acc[4][4];
#pragma unroll
  for (int i = 0; i < 4; ++i)
#pragma unroll
    for (int j = 0; j < 4; ++j) acc[i][j] = (floatx4){0.f, 0.f, 0.f, 0.f};

  const unsigned short* Abase = A + (size_t)bm * 128 * 1024;
  const unsigned short* Wbase = W + (size_t)bn * 128 * 1024;

  for (int k0 = 0; k0 < 1024; k0 += 32) {
    uint2 a2[4], w2[4];
#pragma unroll
    for (int i = 0; i < 4; ++i) {
      const int q = tid + 256 * i;
      const int row = q >> 3, ch = q & 7;
      a2[i] = *(const uint2*)(Abase + (size_t)row * 1024 + k0 + ch * 4);
      w2[i] = *(const uint2*)(Wbase + (size_t)row * 1024 + k0 + ch * 4);
    }
#pragma unroll
    for (int i = 0; i < 4; ++i) {
      const int q = tid + 256 * i;
      const int row = q >> 3, ch = q & 7;
      *(uint2*)(&As[row * 40 + ch * 4]) = a2[i];
      *(uint2*)(&Ws[row * 40 + ch * 4]) = w2[i];
    }
    __syncthreads();
    short8 af[4], wf[4];
#pragma unroll
    for (int i = 0; i < 4; ++i) {
      af[i] = *(const short8*)(&As[(wm + i * 16 + fm) * 40 + quad * 8]);
      wf[i] = *(const short8*)(&Ws[(wn + i * 16 + fm) * 40 + quad * 8]);
    }
#pragma unroll
    for (int i = 0; i < 4; ++i)
#pragma unroll
      for (int j = 0; j < 4; ++j)
        acc[i][j] = __builtin_amdgcn_mfma_f32_16x16x32_bf16(af[i], wf[j], acc[i][j], 0, 0, 0);
    __syncthreads();
  }

  // epilogue: C/D layout col=lane&15, row=quad*4+reg (m89/m91)
#pragma unroll
  for (int i = 0; i < 4; ++i) {
    const int grow0 = bm * 128 + wm + i * 16 + quad * 4;
#pragma unroll
    for (int j = 0; j < 4; ++j) {
      const int gcol = bn * 128 + wn + j * 16 + fm;
#pragma unroll
      for (int r = 0; r < 4; ++r)
        C[(size_t)(grow0 + r) * 1024 + gcol] = acc[i][j][r];
    }
  }
}

// ---------------- fp32-input bf16 MFMA GEMM with sigmoid (gate) ----------------
template<int ACT>
__global__ __launch_bounds__(256) void gemm_bf16_nt(
    const float* __restrict__ A, const float* __restrict__ W,
    const float* __restrict__ bias, float* __restrict__ C)
{
  __shared__ __align__(16) unsigned short As[128 * 40];
  __shared__ __align__(16) unsigned short Ws[128 * 40];
  const int tid  = threadIdx.x;
  const int bn   = blockIdx.x & 7;
  const int bm   = blockIdx.x >> 3;
  const int wave = tid >> 6, lane = tid & 63;
  const int wm = (wave >> 1) * 64, wn = (wave & 1) * 64;
  const int fm = lane & 15, quad = lane >> 4;

  floatx4 acc[4][4];
#pragma unroll
  for (int i = 0; i < 4; ++i)
#pragma unroll
    for (int j = 0; j < 4; ++j) acc[i][j] = (floatx4){0.f, 0.f, 0.f, 0.f};

  const float* Abase = A + (size_t)bm * 128 * 1024;
  const float* Wbase = W + (size_t)bn * 128 * 1024;

  for (int k0 = 0; k0 < 1024; k0 += 32) {
    float4 a4[4], w4[4];
#pragma unroll
    for (int i = 0; i < 4; ++i) {
      const int q = tid + 256 * i;
      const int row = q >> 3, ch = q & 7;
      a4[i] = *(const float4*)(Abase + (size_t)row * 1024 + k0 + ch * 4);
      w4[i] = *(const float4*)(Wbase + (size_t)row * 1024 + k0 + ch * 4);
    }
#pragma unroll
    for (int i = 0; i < 4; ++i) {
      const int q = tid + 256 * i;
      const int row = q >> 3, ch = q & 7;
      uint2 pa, pw;
      pa.x = pack_bf16(a4[i].x, a4[i].y); pa.y = pack_bf16(a4[i].z, a4[i].w);
      pw.x = pack_bf16(w4[i].x, w4[i].y); pw.y = pack_bf16(w4[i].z, w4[i].w);
      *(uint2*)(&As[row * 40 + ch * 4]) = pa;
      *(uint2*)(&Ws[row * 40 + ch * 4]) = pw;
    }
    __syncthreads();
    short8 af[4], wf[4];
#pragma unroll
    for (int i = 0; i < 4; ++i) {
      af[i] = *(const short8*)(&As[(wm + i * 16 + fm) * 40 + quad * 8]);
      wf[i] = *(const short8*)(&Ws[(wn + i * 16 + fm) * 40 + quad * 8]);
    }
#pragma unroll
    for (int i = 0; i < 4; ++i)
#pragma unroll
      for (int j = 0; j < 4; ++j)
        acc[i][j] = __builtin_amdgcn_mfma_f32_16x16x32_bf16(af[i], wf[j], acc[i][j], 0, 0, 0);
    __syncthreads();
  }

  // epilogue: C/D layout col=lane&15, row=quad*4+reg (m89/m91)
#pragma unroll
  for (int i = 0; i < 4; ++i) {
    const int grow0 = bm * 128 + wm + i * 16 + quad * 4;
#pragma unroll
    for (int j = 0; j < 4; ++j) {
      const int gcol = bn * 128 + wn + j * 16 + fm;
      const float bb = (ACT == 1) ? bias[gcol] : 0.f;
#pragma unroll
      for (int r = 0; r < 4; ++r) {
        float v = acc[i][j][r] + bb;
        if (ACT == 1) v = 1.f / (1.f + __expf(-v));
        C[(size_t)(grow0 + r) * 1024 + gcol] = v;
      }
    }
  }
}

// ---------------- readout GEMM, MFMA hi/lo version (W pre-split into bf16 hi/lo) ----------------
// out[gr,e] = blend(gelu(LN(res)[gr,:] . ro_w[e,:] + bias[e]), ssm_recon, gate)
// A*W ~= Ah*Wh + Al*Wh + Ah*Wl (dropped Al*Wl ~2^-17). LN fused into A-staging.
__global__ __launch_bounds__(256) void gemm_readout_mfma(
    const float* __restrict__ A,      // reservoir states [M,1024]
    const unsigned short* __restrict__ Wh_g,  // bf16 hi of ro_w
    const unsigned short* __restrict__ Wl_g,  // bf16 lo of ro_w
    const float* __restrict__ bias,   // ro_bias
    const float2* __restrict__ lnst,  // per-row mean/rstd
    const float* __restrict__ lng, const float* __restrict__ lnb,
    const float* __restrict__ Avec,   // A[h]
    const float* __restrict__ cumd,   // within-chunk cumulative delta [M]
    const float* __restrict__ chH,    // per-chunk initial ssm state [B,16,1024]
    const float* __restrict__ gate,   // [M,1024]
    float* __restrict__ C)            // d_out: in = ssm local states, out = final
{
  __shared__ __align__(16) unsigned short Ah[128 * 40];
  __shared__ __align__(16) unsigned short Al[128 * 40];
  __shared__ __align__(16) unsigned short Wh[128 * 40];
  __shared__ __align__(16) unsigned short Wl[128 * 40];
  const int tid  = threadIdx.x;
  const int bn   = blockIdx.x & 7;
  const int bm   = blockIdx.x >> 3;
  const int wave = tid >> 6, lane = tid & 63;
  const int wm = (wave >> 1) * 64, wn = (wave & 1) * 64;
  const int fm = lane & 15, quad = lane >> 4;

  floatx4 acc[4][4];
#pragma unroll
  for (int i = 0; i < 4; ++i)
#pragma unroll
    for (int j = 0; j < 4; ++j) acc[i][j] = (floatx4){0.f, 0.f, 0.f, 0.f};

  const float* Abase = A + (size_t)bm * 128 * 1024;
  const unsigned short* Whb = Wh_g + (size_t)bn * 128 * 1024;
  const unsigned short* Wlb = Wl_g + (size_t)bn * 128 * 1024;

  // per-thread staged-row stats (row fixed per i across k-tiles)
  float2 st_i[4];
#pragma unroll
  for (int i = 0; i < 4; ++i) {
    const int q = tid + 256 * i;
    st_i[i] = lnst[bm * 128 + (q >> 3)];
  }

  for (int k0 = 0; k0 < 1024; k0 += 32) {
#pragma unroll
    for (int i = 0; i < 4; ++i) {
      const int q = tid + 256 * i;
      const int row = q >> 3, ch = q & 7;
      float4 a4 = *(const float4*)(Abase + (size_t)row * 1024 + k0 + ch * 4);
      const float4 g4 = *(const float4*)(lng + k0 + ch * 4);
      const float4 b4 = *(const float4*)(lnb + k0 + ch * 4);
      const float2 st = st_i[i];
      a4.x = (a4.x - st.x) * st.y * g4.x + b4.x;
      a4.y = (a4.y - st.x) * st.y * g4.y + b4.y;
      a4.z = (a4.z - st.x) * st.y * g4.z + b4.z;
      a4.w = (a4.w - st.x) * st.y * g4.w + b4.w;
      // hi/lo split of A
      const float av[4] = {a4.x, a4.y, a4.z, a4.w};
      unsigned ah[4]; float alr[4];
#pragma unroll
      for (int e = 0; e < 4; ++e) {
        ah[e] = (__float_as_uint(av[e]) + 0x8000u) & 0xFFFF0000u;
        alr[e] = av[e] - __uint_as_float(ah[e]);
      }
      uint2 pah, pal;
      pah.x = pack_hi16(ah[0], ah[1]); pah.y = pack_hi16(ah[2], ah[3]);
      pal.x = pack_bf16(alr[0], alr[1]); pal.y = pack_bf16(alr[2], alr[3]);
      *(uint2*)(&Ah[row * 40 + ch * 4]) = pah;
      *(uint2*)(&Al[row * 40 + ch * 4]) = pal;
      // W: pre-split, plain copies
      *(uint2*)(&Wh[row * 40 + ch * 4]) = *(const uint2*)(Whb + (size_t)row * 1024 + k0 + ch * 4);
      *(uint2*)(&Wl[row * 40 + ch * 4]) = *(const uint2*)(Wlb + (size_t)row * 1024 + k0 + ch * 4);
    }
    __syncthreads();
    short8 afh[4], afl[4], wfh[4], wfl[4];
#pragma unroll
    for (int i = 0; i < 4; ++i) {
      const int ao = (wm + i * 16 + fm) * 40 + quad * 8;
      const int wo = (wn + i * 16 + fm) * 40 + quad * 8;
      afh[i] = *(const short8*)(&Ah[ao]);
      afl[i] = *(const short8*)(&Al[ao]);
      wfh[i] = *(const short8*)(&Wh[wo]);
      wfl[i] = *(const short8*)(&Wl[wo]);
    }
#pragma unroll
    for (int i = 0; i < 4; ++i)
#pragma unroll
      for (int j = 0; j < 4; ++j) {
        acc[i][j] = __builtin_amdgcn_mfma_f32_16x16x32_bf16(afh[i], wfh[j], acc[i][j], 0, 0, 0);
        acc[i][j] = __builtin_amdgcn_mfma_f32_16x16x32_bf16(afl[i], wfh[j], acc[i][j], 0, 0, 0);
        acc[i][j] = __builtin_amdgcn_mfma_f32_16x16x32_bf16(afh[i], wfl[j], acc[i][j], 0, 0, 0);
      }
    __syncthreads();
  }

  // epilogue: C/D layout col=lane&15, row=quad*4+reg; gelu + ssm recon + gate blend
#pragma unroll
  for (int i = 0; i < 4; ++i) {
    const int grow0 = bm * 128 + wm + i * 16 + quad * 4;
    float cd_r[4];
    int hb_r[4];
#pragma unroll
    for (int r = 0; r < 4; ++r) {
      const int gr = grow0 + r;
      const int b = gr >> 11;           // gr = b*2048 + s
      const int c = (gr & 2047) >> 7;   // 128-step chunk
      cd_r[r] = cumd[gr];
      hb_r[r] = (b * 16 + c) << 10;
    }
#pragma unroll
    for (int j = 0; j < 4; ++j) {
      const int gcol = bn * 128 + wn + j * 16 + fm;
      const float Ae = Avec[gcol];
      const float bb = bias[gcol];
#pragma unroll
      for (int r = 0; r < 4; ++r) {
        const int gr = grow0 + r;
        const size_t off = (size_t)gr * 1024 + gcol;
        const float hin = chH[hb_r[r] + gcol];
        const float lcl = C[off];
        const float gt  = gate[off];
        float v = acc[i][j][r] + bb;
        v = 0.5f * v * (1.f + erff(v * 0.70710678118654752f));   // exact gelu
        const float p = __expf(Ae * cd_r[r]);                    // prod of A_bar over chunk prefix
        const float sst = lcl + p * hin;                         // true ssm state
        C[off] = v * gt + sst * (1.f - gt);
      }
    }
  }
}

// ---------------- reservoir scan: persistent 16-WG x 512-thread kernel (v4, proven) ----------------
// Exchange protocol: self-certifying words bf16(h)<<16|tag, relaxed AGENT-scope atomics,
// global parity buffers, zeroed before launch.
//   * 16 WGs x 64 rows, 8 waves; wave = 16 rows x K-half, hi/lo bf16 W frags (128 VGPR).
//   * red tile stores the two K-half partials ADJACENT -> combine is ONE ds_read_b64.
//   * only fm<8 lanes write red; no s_sleep in the poll.
//   * dbuf LDS h-tile; 2 barriers/step; hprev in register; u prefetched before the poll;
//     fast tanh. Tail is 64-lane COALESCED (one 4B store per thread) — v5 showed scattered
//     16B tails cost +0.76us/step in partial-line HBM traffic.
// Safety: thread stores tag s+1 only after barrier#2(s) which post-dates ALL its WG's tag-s
// polls; a WG stores tag s+2 (overwriting parity buffer s) only after poll(s+1) success,
// which certifies every WG passed barrier#2(s). LDS reuse separated by >=1 barrier.
__global__ __launch_bounds__(512, 2) void reservoir_scan_kernel(
    float* __restrict__ xin_res,       // [8][2048][1024]: in xin, out res states (in-place)
    const float* __restrict__ Wres,    // [1024][1024]
    unsigned* __restrict__ hbuf,       // [2][8192] packed words, zeroed before launch
    unsigned* __restrict__ unused)
{
  const int tid  = threadIdx.x;
  const int wg   = blockIdx.x;         // 0..15
  const int g    = tid >> 6;           // wave 0..7
  const int lane = tid & 63;
  const int fm   = lane & 15;          // MFMA m (A row) / n (C col)
  const int quad = lane >> 4;          // MFMA k-quad
  const int rowb = wg * 64 + (g & 3) * 16;   // wave's 16-row tile
  const int kh   = (g >> 2) * 512;     // wave's K-half

  __shared__ __align__(16) unsigned short hbf[2][8 * 1040];  // dbuf bf16 h, padded batch stride
  __shared__ float red[1184];          // [rt(4):296][m(16):18][b(8):2][kh(2):1]

  // ---- W fragments: 16 rows x 512 K per wave, hi/lo bf16 split (128 VGPRs) ----
  short8 whi[16], wlo[16];
  {
    const float* wrow = Wres + (size_t)(rowb + fm) * 1024 + kh + quad * 8;
#pragma unroll
    for (int k0 = 0; k0 < 16; ++k0) {
      const float4 wa = *(const float4*)(wrow + k0 * 32);
      const float4 wb = *(const float4*)(wrow + k0 * 32 + 4);
      const float wv[8] = {wa.x, wa.y, wa.z, wa.w, wb.x, wb.y, wb.z, wb.w};
      short8 h8, l8;
#pragma unroll
      for (int j = 0; j < 8; ++j) {
        const unsigned bits = __float_as_uint(wv[j]);
        const unsigned hb   = (bits + 0x8000u) & 0xFFFF0000u;
        const float    lo   = wv[j] - __uint_as_float(hb);
        h8[j] = (short)(hb >> 16);
        l8[j] = (short)((__float_as_uint(lo) + 0x8000u) >> 16);
      }
      whi[k0] = h8; wlo[k0] = l8;
    }
  }

  const int bb    = fm & 7;            // B-frag batch (C cols 8..15 duplicate, discarded)
  const int r_out = tid & 63;          // this thread's output row within WG (= lane)
  const int b_out = tid >> 6;          // this thread's output batch (= wave)
  const int jrow  = wg * 64 + r_out;
  float hprev = 0.f;

  const int xw = tid >> 2;             // staging: k-block of this thread's pair (k = 2*tid)
  const int ow = (tid & 3) * 2;        // offset within 8-short block

  for (int s = 0; s < S_; ++s) {
    // ---- prefetch u before the poll (keep-alive pins issue order) ----
    const float u = xin_res[((size_t)b_out * S_ + s) * H_ + jrow];
    asm volatile("" :: "v"(u));

    // ---- poll+load h^s: 8x u64 coalesced; both 16-bit tags must equal s ----
    const unsigned tag = (unsigned)s & 0xFFFFu;
    const unsigned long long tag2 = (unsigned long long)tag | ((unsigned long long)tag << 32);
    const unsigned long long* hp8 =
        (const unsigned long long*)(hbuf + (size_t)(s & 1) * 8192) + tid;  // pair idx tid+512*i
    unsigned long long w8[8];
    for (;;) {
      bool ok = true;
#pragma unroll
      for (int i = 0; i < 8; ++i)
        w8[i] = __hip_atomic_load(hp8 + 512 * i, __ATOMIC_RELAXED, __HIP_MEMORY_SCOPE_AGENT);
#pragma unroll
      for (int i = 0; i < 8; ++i)
        ok &= (((w8[i] ^ tag2) & 0x0000FFFF0000FFFFull) == 0ull);
      if (ok) break;
    }

    // ---- stage h^s to LDS buffer s&1: pair (k=2*tid, 2*tid+1) for each batch ----
    {
      unsigned short* hb = &hbf[s & 1][0];
#pragma unroll
      for (int b = 0; b < 8; ++b) {
        const unsigned lo = (unsigned)(w8[b]);
        const unsigned hi = (unsigned)(w8[b] >> 32);
        const unsigned pk = __builtin_amdgcn_perm(hi, lo, 0x07060302u);  // (bf16 k, bf16 k+1)
        *(unsigned*)(hb + b * 1040 + ((xw ^ b) << 3) + ow) = pk;
      }
    }
    __syncthreads();                   // barrier#1: staged; all polls done before any tag store

    // ---- MFMA matvec: wave's 16 rows x 8 batches over its K-half ----
    const unsigned short* hrow = &hbf[s & 1][bb * 1040];
    floatx4 acc[8];
#pragma unroll
    for (int i = 0; i < 8; ++i) acc[i] = (floatx4){0.f, 0.f, 0.f, 0.f};
#pragma unroll
    for (int k0 = 0; k0 < 16; ++k0) {
      const int X = (g >> 2) * 64 + k0 * 4 + quad;   // global 8-block index of this k-frag
      const short8 hb8 = *(const short8*)(hrow + ((X ^ bb) << 3));
      acc[(2 * k0)     & 7] = __builtin_amdgcn_mfma_f32_16x16x32_bf16(whi[k0], hb8, acc[(2 * k0)     & 7], 0, 0, 0);
      acc[(2 * k0 + 1) & 7] = __builtin_amdgcn_mfma_f32_16x16x32_bf16(wlo[k0], hb8, acc[(2 * k0 + 1) & 7], 0, 0, 0);
    }
    // C layout: col=lane&15, row=quad*4+r — write K-half partials, pair-adjacent
    if (fm < 8) {
      float csum[4];
#pragma unroll
      for (int r = 0; r < 4; ++r)
        csum[r] = ((acc[0][r] + acc[1][r]) + (acc[2][r] + acc[3][r]))
                + ((acc[4][r] + acc[5][r]) + (acc[6][r] + acc[7][r]));
      float* rw = red + (g & 3) * 296 + (quad * 4) * 18 + bb * 2 + (g >> 2);
#pragma unroll
      for (int r = 0; r < 4; ++r) rw[r * 18] = csum[r];
    }
    __syncthreads();                   // barrier#2: red tile complete

    // ---- combine K-halves (one b64), tanh, leak, handoff store first ----
    {
      const float2 dd = *(const float2*)(red + (r_out >> 4) * 296 + (r_out & 15) * 18 + b_out * 2);
      const float z  = u + dd.x + dd.y;
      const float e  = __expf(2.f * z);                 // tanh(z) = 1 - 2/(e^{2z}+1)
      const float hn = 1.f - __fdividef(2.f, e + 1.f);  // saturates correctly
      const float hv = 0.95f * hn + 0.05f * hprev;
      hprev = hv;
      const unsigned word = ((__float_as_uint(hv) + 0x8000u) & 0xFFFF0000u)
                          | ((unsigned)(s + 1) & 0xFFFFu);
      __hip_atomic_store(hbuf + (size_t)((s + 1) & 1) * 8192 + (size_t)b_out * 1024 + jrow,
                         word, __ATOMIC_RELAXED, __HIP_MEMORY_SCOPE_AGENT);
      xin_res[((size_t)b_out * S_ + s) * H_ + jrow] = hv;   // full fp32 to readout path
    }
    // no drain, no flag, no rendezvous — next iteration's poll is the wait
  }
}

// ---------------- SSM chunked scan ----------------
// within-chunk cumulative delta (tiny)
__global__ __launch_bounds__(128) void cumd_kernel(
    const float* __restrict__ delta, float* __restrict__ cumd)
{
  const int t = threadIdx.x;          // 128 = 8 batches * 16 chunks
  const int b = t >> 4, c = t & 15;
  const int base = b * S_ + c * 128;
  float acc = 0.f;
  for (int i = 0; i < 128; ++i) { acc += delta[base + i]; cumd[base + i] = acc; }
}

// phase A: per-chunk local scan, in-place Bx -> local states; store chunk products
__global__ __launch_bounds__(256) void ssm_partial_kernel(
    const float* __restrict__ delta, const float* __restrict__ Avec,
    float* __restrict__ bx, float* __restrict__ P)
{
  const int idx = blockIdx.x * 256 + threadIdx.x;
  const int h = idx & 1023;
  const int c = (idx >> 10) & 15;
  const int b = idx >> 14;
  const float Ah = Avec[h];
  const float inv = 1.f / (Ah + 1e-8f);
  const float* dp = delta + b * S_ + c * 128;
  float* xp = bx + ((size_t)(b * S_ + c * 128)) * H_ + h;
  float p = 1.f, hl = 0.f;
  for (int t = 0; t < 128; ++t) {
    const float a = __expf(Ah * dp[t]);
    const float bb = xp[(size_t)t * H_] * (1.f - a) * inv;
    hl = a * hl + bb;
    p *= a;
    xp[(size_t)t * H_] = hl;
  }
  P[(b * 16 + c) * 1024 + h] = p;
}

// phase B: sequential combine over 16 chunks -> per-chunk initial states
__global__ __launch_bounds__(256) void ssm_combine_kernel(
    const float* __restrict__ P, const float* __restrict__ local, float* __restrict__ Hin)
{
  const int idx = blockIdx.x * 256 + threadIdx.x;  // 8192
  const int h = idx & 1023;
  const int b = idx >> 10;
  float hh = 0.f;
#pragma unroll
  for (int c = 0; c < 16; ++c) {
    const int o = (b * 16 + c) * 1024 + h;
    Hin[o] = hh;
    hh = P[o] * hh + local[((size_t)(b * S_ + c * 128 + 127)) * H_ + h];
  }
}

// ---------------- host launch ----------------
extern "C" void kernel_launch(void* const* d_in, const int* in_sizes, int n_in,
                              void* d_out, int out_size, void* d_ws, size_t ws_size,
                              hipStream_t stream) {
  (void)in_sizes; (void)n_in; (void)out_size; (void)ws_size;
  const float* x      = (const float*)d_in[0];
  const float* W_in   = (const float*)d_in[1];
  const float* W_res  = (const float*)d_in[2];
  const float* norm_g = (const float*)d_in[3];
  const float* norm_b = (const float*)d_in[4];
  const float* dw     = (const float*)d_in[5];
  const float* db     = (const float*)d_in[6];
  const float* Avec   = (const float*)d_in[7];
  const float* B_w    = (const float*)d_in[8];
  const float* ro_g   = (const float*)d_in[9];
  const float* ro_b   = (const float*)d_in[10];
  const float* ro_w   = (const float*)d_in[11];
  const float* ro_bias= (const float*)d_in[12];
  const float* gate_w = (const float*)d_in[13];
  const float* gate_b = (const float*)d_in[14];
  float* out = (float*)d_out;
  float* ws  = (float*)d_ws;

  float*    buf0   = ws;                    // bf16 x_norm (first 32MB), later fp32 gate (64MB)
  float*    buf1   = ws + 16777216;         // xin -> reservoir states (in-place)
  float*    delta  = ws + 33554432;         // [M]
  float*    cumd   = ws + 33570816;         // [M]
  unsigned* hbuf   = (unsigned*)(ws + 33587200);  // [2][8192] packed words
  float2*   stats  = (float2*)(ws + 33603712);
  float*    chP    = ws + 33636480;         // [B,16,1024]
  float*    chH    = ws + 33767552;         // [B,16,1024]
  unsigned short* xnb = (unsigned short*)buf0;            // bf16 x_norm [M,1024]
  unsigned short* wib = (unsigned short*)(ws + 33898624); // bf16 W_in   [1024,1024]
  unsigned short* bwb = (unsigned short*)(ws + 34422912); // bf16 B_w
  unsigned short* roh = (unsigned short*)(ws + 34947200); // bf16 hi(ro_w)
  unsigned short* rol = (unsigned short*)(ws + 35471488); // bf16 lo(ro_w)

  // 0. weight conversions (once per launch, tiny)
  tobf16_kernel<<<1024, 256, 0, stream>>>(W_in, wib);
  tobf16_kernel<<<1024, 256, 0, stream>>>(B_w, bwb);
  splitw_kernel<<<1024, 256, 0, stream>>>(ro_w, roh, rol);
  // 1. layernorm -> bf16 x_norm + delta
  ln_delta_kernel<<<M_, 256, 0, stream>>>(x, norm_g, norm_b, dw, db, xnb, delta);
  // 2. xin = x_norm @ W_in^T   -> buf1   (bf16 x bf16 MFMA)
  gemm_bb<<<1024, 256, 0, stream>>>(xnb, wib, buf1);
  // 3. Bx = x_norm @ B_w^T     -> d_out (scratch)
  gemm_bb<<<1024, 256, 0, stream>>>(xnb, bwb, out);
  // 4. gate = sigmoid(x @ gate_w^T + gate_b) -> buf0 (xnb dead)   (fp32-input path)
  gemm_bf16_nt<1><<<1024, 256, 0, stream>>>(x, gate_w, gate_b, buf0);
  // 5. ssm chunked scan pieces (independent of reservoir)
  cumd_kernel<<<1, 128, 0, stream>>>(delta, cumd);
  ssm_partial_kernel<<<512, 256, 0, stream>>>(delta, Avec, out, chP);
  ssm_combine_kernel<<<32, 256, 0, stream>>>(chP, out, chH);
  // 6. reservoir scan (zero both parity buffers: word 0 == tag 0 | bf16(0))
  hipMemsetAsync(hbuf, 0, 2 * 8192 * sizeof(unsigned), stream);
  reservoir_scan_kernel<<<16, 512, 0, stream>>>(buf1, W_res, hbuf, nullptr);
  // 7. ro-layernorm stats
  rowstats_kernel<<<M_, 256, 0, stream>>>(buf1, stats);
  // 8. readout GEMM (MFMA hi/lo, pre-split W) + gelu + ssm recon + gate blend -> d_out
  gemm_readout_mfma<<<1024, 256, 0, stream>>>(buf1, roh, rol, ro_bias, stats, ro_g, ro_b,
                                              Avec, cumd, chH, buf0, out);
}

// Round 7
// 4135.253 us; speedup vs baseline: 1.6030x; 1.2227x over previous
//
#include <hip/hip_runtime.h>
#include <math.h>

#define B_ 8
#define S_ 2048
#define E_ 1024
#define H_ 1024
#define M_ 16384   // B_*S_

typedef __attribute__((ext_vector_type(8))) short short8;    // 8 bf16 = 4 VGPRs
typedef __attribute__((ext_vector_type(4))) float floatx4;

// ---------------- block-wide reduction of two floats (256 threads = 4 waves) ----------------
__device__ __forceinline__ void block_reduce2(float &a, float &b) {
#pragma unroll
  for (int off = 32; off > 0; off >>= 1) {
    a += __shfl_down(a, off);
    b += __shfl_down(b, off);
  }
  __shared__ float sa[4], sb[4];
  const int w = threadIdx.x >> 6;
  __syncthreads();                 // protects reuse across back-to-back calls
  if ((threadIdx.x & 63) == 0) { sa[w] = a; sb[w] = b; }
  __syncthreads();
  a = sa[0] + sa[1] + sa[2] + sa[3];
  b = sb[0] + sb[1] + sb[2] + sb[3];
}

__device__ __forceinline__ unsigned pack_bf16(float lo, float hi) {
  return __builtin_amdgcn_perm(__float_as_uint(hi) + 0x8000u,
                               __float_as_uint(lo) + 0x8000u, 0x07060302u);
}
// pack the hi16 of two u32 bit patterns: (hi16(a) in low half, hi16(b) in high half)
__device__ __forceinline__ unsigned pack_hi16(unsigned a, unsigned b) {
  return __builtin_amdgcn_perm(b, a, 0x07060302u);
}

// ---------------- LayerNorm(x) -> x_norm (bf16!), plus delta = softplus(x_norm . delta_w + db) ----------------
__global__ __launch_bounds__(256) void ln_delta_kernel(
    const float* __restrict__ x, const float* __restrict__ g, const float* __restrict__ bt,
    const float* __restrict__ dw, const float* __restrict__ db,
    unsigned short* __restrict__ xnb, float* __restrict__ delta)
{
  const int row = blockIdx.x;
  const int t = threadIdx.x;
  const float4 v = ((const float4*)(x + (size_t)row * E_))[t];
  float s1 = v.x + v.y + v.z + v.w;
  float s2 = v.x*v.x + v.y*v.y + v.z*v.z + v.w*v.w;
  block_reduce2(s1, s2);
  const float mean = s1 * (1.f / E_);
  const float var  = s2 * (1.f / E_) - mean * mean;
  const float rstd = rsqrtf(var + 1e-5f);
  const float4 g4 = ((const float4*)g)[t];
  const float4 b4 = ((const float4*)bt)[t];
  float4 o;
  o.x = (v.x - mean) * rstd * g4.x + b4.x;
  o.y = (v.y - mean) * rstd * g4.y + b4.y;
  o.z = (v.z - mean) * rstd * g4.z + b4.z;
  o.w = (v.w - mean) * rstd * g4.w + b4.w;
  uint2 p;
  p.x = pack_bf16(o.x, o.y); p.y = pack_bf16(o.z, o.w);
  ((uint2*)(xnb + (size_t)row * E_))[t] = p;       // bf16 x_norm (same rounding the GEMMs used)
  const float4 d4 = ((const float4*)dw)[t];
  float dd = o.x*d4.x + o.y*d4.y + o.z*d4.z + o.w*d4.w;   // delta stays fp32-accurate
  float dummy = 0.f;
  block_reduce2(dd, dummy);
  if (t == 0) {
    const float z = dd + db[0];
    delta[row] = (z > 20.f) ? z : log1pf(__expf(z));
  }
}

// ---------------- per-row mean/rstd of reservoir states (for fused ro-layernorm) ----------------
__global__ __launch_bounds__(256) void rowstats_kernel(
    const float* __restrict__ res, float2* __restrict__ st)
{
  const int row = blockIdx.x;
  const int t = threadIdx.x;
  const float4 v = ((const float4*)(res + (size_t)row * H_))[t];
  float s1 = v.x + v.y + v.z + v.w;
  float s2 = v.x*v.x + v.y*v.y + v.z*v.z + v.w*v.w;
  block_reduce2(s1, s2);
  if (t == 0) {
    const float m = s1 * (1.f / H_);
    const float var = s2 * (1.f / H_) - m * m;
    st[row] = make_float2(m, rsqrtf(var + 1e-5f));
  }
}

// ---------------- tiny converters (run once, off critical path) ----------------
__global__ __launch_bounds__(256) void tobf16_kernel(
    const float* __restrict__ s, unsigned short* __restrict__ d)
{
  const int i = blockIdx.x * 256 + threadIdx.x;
  const float4 v = ((const float4*)s)[i];
  uint2 p;
  p.x = pack_bf16(v.x, v.y); p.y = pack_bf16(v.z, v.w);
  ((uint2*)d)[i] = p;
}

__global__ __launch_bounds__(256) void splitw_kernel(
    const float* __restrict__ s, unsigned short* __restrict__ dh, unsigned short* __restrict__ dl)
{
  const int i = blockIdx.x * 256 + threadIdx.x;
  const float4 v = ((const float4*)s)[i];
  const float sv[4] = {v.x, v.y, v.z, v.w};
  unsigned h[4]; float l[4];
#pragma unroll
  for (int e = 0; e < 4; ++e) {
    h[e] = (__float_as_uint(sv[e]) + 0x8000u) & 0xFFFF0000u;
    l[e] = sv[e] - __uint_as_float(h[e]);
  }
  uint2 ph, pl;
  ph.x = pack_hi16(h[0], h[1]); ph.y = pack_hi16(h[2], h[3]);
  pl.x = pack_bf16(l[0], l[1]); pl.y = pack_bf16(l[2], l[3]);
  ((uint2*)dh)[i] = ph;
  ((uint2*)dl)[i] = pl;
}

// ---------------- bf16-input MFMA GEMM: C[M,N] = A[M,1024] @ W[N,1024]^T (A,W bf16) ----------------
__global__ __launch_bounds__(256) void gemm_bb(
    const unsigned short* __restrict__ A, const unsigned short* __restrict__ W,
    float* __restrict__ C)
{
  __shared__ __align__(16) unsigned short As[128 * 40];
  __shared__ __align__(16) unsigned short Ws[128 * 40];
  const int tid  = threadIdx.x;
  const int bn   = blockIdx.x & 7;
  const int bm   = blockIdx.x >> 3;
  const int wave = tid >> 6, lane = tid & 63;
  const int wm = (wave >> 1) * 64, wn = (wave & 1) * 64;
  const int fm = lane & 15, quad = lane >> 4;

  floatx4 acc[4][4];
#pragma unroll
  for (int i = 0; i < 4; ++i)
#pragma unroll
    for (int j = 0; j < 4; ++j) acc[i][j] = (floatx4){0.f, 0.f, 0.f, 0.f};

  const unsigned short* Abase = A + (size_t)bm * 128 * 1024;
  const unsigned short* Wbase = W + (size_t)bn * 128 * 1024;

  for (int k0 = 0; k0 < 1024; k0 += 32) {
    uint2 a2[4], w2[4];
#pragma unroll
    for (int i = 0; i < 4; ++i) {
      const int q = tid + 256 * i;
      const int row = q >> 3, ch = q & 7;
      a2[i] = *(const uint2*)(Abase + (size_t)row * 1024 + k0 + ch * 4);
      w2[i] = *(const uint2*)(Wbase + (size_t)row * 1024 + k0 + ch * 4);
    }
#pragma unroll
    for (int i = 0; i < 4; ++i) {
      const int q = tid + 256 * i;
      const int row = q >> 3, ch = q & 7;
      *(uint2*)(&As[row * 40 + ch * 4]) = a2[i];
      *(uint2*)(&Ws[row * 40 + ch * 4]) = w2[i];
    }
    __syncthreads();
    short8 af[4], wf[4];
#pragma unroll
    for (int i = 0; i < 4; ++i) {
      af[i] = *(const short8*)(&As[(wm + i * 16 + fm) * 40 + quad * 8]);
      wf[i] = *(const short8*)(&Ws[(wn + i * 16 + fm) * 40 + quad * 8]);
    }
#pragma unroll
    for (int i = 0; i < 4; ++i)
#pragma unroll
      for (int j = 0; j < 4; ++j)
        acc[i][j] = __builtin_amdgcn_mfma_f32_16x16x32_bf16(af[i], wf[j], acc[i][j], 0, 0, 0);
    __syncthreads();
  }

  // epilogue: C/D layout col=lane&15, row=quad*4+reg (m89/m91)
#pragma unroll
  for (int i = 0; i < 4; ++i) {
    const int grow0 = bm * 128 + wm + i * 16 + quad * 4;
#pragma unroll
    for (int j = 0; j < 4; ++j) {
      const int gcol = bn * 128 + wn + j * 16 + fm;
#pragma unroll
      for (int r = 0; r < 4; ++r)
        C[(size_t)(grow0 + r) * 1024 + gcol] = acc[i][j][r];
    }
  }
}

// ---------------- fp32-input bf16 MFMA GEMM with sigmoid (gate) ----------------
template<int ACT>
__global__ __launch_bounds__(256) void gemm_bf16_nt(
    const float* __restrict__ A, const float* __restrict__ W,
    const float* __restrict__ bias, float* __restrict__ C)
{
  __shared__ __align__(16) unsigned short As[128 * 40];
  __shared__ __align__(16) unsigned short Ws[128 * 40];
  const int tid  = threadIdx.x;
  const int bn   = blockIdx.x & 7;
  const int bm   = blockIdx.x >> 3;
  const int wave = tid >> 6, lane = tid & 63;
  const int wm = (wave >> 1) * 64, wn = (wave & 1) * 64;
  const int fm = lane & 15, quad = lane >> 4;

  floatx4 acc[4][4];
#pragma unroll
  for (int i = 0; i < 4; ++i)
#pragma unroll
    for (int j = 0; j < 4; ++j) acc[i][j] = (floatx4){0.f, 0.f, 0.f, 0.f};

  const float* Abase = A + (size_t)bm * 128 * 1024;
  const float* Wbase = W + (size_t)bn * 128 * 1024;

  for (int k0 = 0; k0 < 1024; k0 += 32) {
    float4 a4[4], w4[4];
#pragma unroll
    for (int i = 0; i < 4; ++i) {
      const int q = tid + 256 * i;
      const int row = q >> 3, ch = q & 7;
      a4[i] = *(const float4*)(Abase + (size_t)row * 1024 + k0 + ch * 4);
      w4[i] = *(const float4*)(Wbase + (size_t)row * 1024 + k0 + ch * 4);
    }
#pragma unroll
    for (int i = 0; i < 4; ++i) {
      const int q = tid + 256 * i;
      const int row = q >> 3, ch = q & 7;
      uint2 pa, pw;
      pa.x = pack_bf16(a4[i].x, a4[i].y); pa.y = pack_bf16(a4[i].z, a4[i].w);
      pw.x = pack_bf16(w4[i].x, w4[i].y); pw.y = pack_bf16(w4[i].z, w4[i].w);
      *(uint2*)(&As[row * 40 + ch * 4]) = pa;
      *(uint2*)(&Ws[row * 40 + ch * 4]) = pw;
    }
    __syncthreads();
    short8 af[4], wf[4];
#pragma unroll
    for (int i = 0; i < 4; ++i) {
      af[i] = *(const short8*)(&As[(wm + i * 16 + fm) * 40 + quad * 8]);
      wf[i] = *(const short8*)(&Ws[(wn + i * 16 + fm) * 40 + quad * 8]);
    }
#pragma unroll
    for (int i = 0; i < 4; ++i)
#pragma unroll
      for (int j = 0; j < 4; ++j)
        acc[i][j] = __builtin_amdgcn_mfma_f32_16x16x32_bf16(af[i], wf[j], acc[i][j], 0, 0, 0);
    __syncthreads();
  }

  // epilogue: C/D layout col=lane&15, row=quad*4+reg (m89/m91)
#pragma unroll
  for (int i = 0; i < 4; ++i) {
    const int grow0 = bm * 128 + wm + i * 16 + quad * 4;
#pragma unroll
    for (int j = 0; j < 4; ++j) {
      const int gcol = bn * 128 + wn + j * 16 + fm;
      const float bb = (ACT == 1) ? bias[gcol] : 0.f;
#pragma unroll
      for (int r = 0; r < 4; ++r) {
        float v = acc[i][j][r] + bb;
        if (ACT == 1) v = 1.f / (1.f + __expf(-v));
        C[(size_t)(grow0 + r) * 1024 + gcol] = v;
      }
    }
  }
}

// ---------------- readout GEMM, MFMA hi/lo version (W pre-split into bf16 hi/lo) ----------------
// out[gr,e] = blend(gelu(LN(res)[gr,:] . ro_w[e,:] + bias[e]), ssm_recon, gate)
// A*W ~= Ah*Wh + Al*Wh + Ah*Wl (dropped Al*Wl ~2^-17). LN fused into A-staging.
__global__ __launch_bounds__(256) void gemm_readout_mfma(
    const float* __restrict__ A,      // reservoir states [M,1024]
    const unsigned short* __restrict__ Wh_g,  // bf16 hi of ro_w
    const unsigned short* __restrict__ Wl_g,  // bf16 lo of ro_w
    const float* __restrict__ bias,   // ro_bias
    const float2* __restrict__ lnst,  // per-row mean/rstd
    const float* __restrict__ lng, const float* __restrict__ lnb,
    const float* __restrict__ Avec,   // A[h]
    const float* __restrict__ cumd,   // within-chunk cumulative delta [M]
    const float* __restrict__ chH,    // per-chunk initial ssm state [B,16,1024]
    const float* __restrict__ gate,   // [M,1024]
    float* __restrict__ C)            // d_out: in = ssm local states, out = final
{
  __shared__ __align__(16) unsigned short Ah[128 * 40];
  __shared__ __align__(16) unsigned short Al[128 * 40];
  __shared__ __align__(16) unsigned short Wh[128 * 40];
  __shared__ __align__(16) unsigned short Wl[128 * 40];
  const int tid  = threadIdx.x;
  const int bn   = blockIdx.x & 7;
  const int bm   = blockIdx.x >> 3;
  const int wave = tid >> 6, lane = tid & 63;
  const int wm = (wave >> 1) * 64, wn = (wave & 1) * 64;
  const int fm = lane & 15, quad = lane >> 4;

  floatx4 acc[4][4];
#pragma unroll
  for (int i = 0; i < 4; ++i)
#pragma unroll
    for (int j = 0; j < 4; ++j) acc[i][j] = (floatx4){0.f, 0.f, 0.f, 0.f};

  const float* Abase = A + (size_t)bm * 128 * 1024;
  const unsigned short* Whb = Wh_g + (size_t)bn * 128 * 1024;
  const unsigned short* Wlb = Wl_g + (size_t)bn * 128 * 1024;

  // per-thread staged-row stats (row fixed per i across k-tiles)
  float2 st_i[4];
#pragma unroll
  for (int i = 0; i < 4; ++i) {
    const int q = tid + 256 * i;
    st_i[i] = lnst[bm * 128 + (q >> 3)];
  }

  for (int k0 = 0; k0 < 1024; k0 += 32) {
#pragma unroll
    for (int i = 0; i < 4; ++i) {
      const int q = tid + 256 * i;
      const int row = q >> 3, ch = q & 7;
      float4 a4 = *(const float4*)(Abase + (size_t)row * 1024 + k0 + ch * 4);
      const float4 g4 = *(const float4*)(lng + k0 + ch * 4);
      const float4 b4 = *(const float4*)(lnb + k0 + ch * 4);
      const float2 st = st_i[i];
      a4.x = (a4.x - st.x) * st.y * g4.x + b4.x;
      a4.y = (a4.y - st.x) * st.y * g4.y + b4.y;
      a4.z = (a4.z - st.x) * st.y * g4.z + b4.z;
      a4.w = (a4.w - st.x) * st.y * g4.w + b4.w;
      // hi/lo split of A
      const float av[4] = {a4.x, a4.y, a4.z, a4.w};
      unsigned ah[4]; float alr[4];
#pragma unroll
      for (int e = 0; e < 4; ++e) {
        ah[e] = (__float_as_uint(av[e]) + 0x8000u) & 0xFFFF0000u;
        alr[e] = av[e] - __uint_as_float(ah[e]);
      }
      uint2 pah, pal;
      pah.x = pack_hi16(ah[0], ah[1]); pah.y = pack_hi16(ah[2], ah[3]);
      pal.x = pack_bf16(alr[0], alr[1]); pal.y = pack_bf16(alr[2], alr[3]);
      *(uint2*)(&Ah[row * 40 + ch * 4]) = pah;
      *(uint2*)(&Al[row * 40 + ch * 4]) = pal;
      // W: pre-split, plain copies
      *(uint2*)(&Wh[row * 40 + ch * 4]) = *(const uint2*)(Whb + (size_t)row * 1024 + k0 + ch * 4);
      *(uint2*)(&Wl[row * 40 + ch * 4]) = *(const uint2*)(Wlb + (size_t)row * 1024 + k0 + ch * 4);
    }
    __syncthreads();
    short8 afh[4], afl[4], wfh[4], wfl[4];
#pragma unroll
    for (int i = 0; i < 4; ++i) {
      const int ao = (wm + i * 16 + fm) * 40 + quad * 8;
      const int wo = (wn + i * 16 + fm) * 40 + quad * 8;
      afh[i] = *(const short8*)(&Ah[ao]);
      afl[i] = *(const short8*)(&Al[ao]);
      wfh[i] = *(const short8*)(&Wh[wo]);
      wfl[i] = *(const short8*)(&Wl[wo]);
    }
#pragma unroll
    for (int i = 0; i < 4; ++i)
#pragma unroll
      for (int j = 0; j < 4; ++j) {
        acc[i][j] = __builtin_amdgcn_mfma_f32_16x16x32_bf16(afh[i], wfh[j], acc[i][j], 0, 0, 0);
        acc[i][j] = __builtin_amdgcn_mfma_f32_16x16x32_bf16(afl[i], wfh[j], acc[i][j], 0, 0, 0);
        acc[i][j] = __builtin_amdgcn_mfma_f32_16x16x32_bf16(afh[i], wfl[j], acc[i][j], 0, 0, 0);
      }
    __syncthreads();
  }

  // epilogue: C/D layout col=lane&15, row=quad*4+reg; gelu + ssm recon + gate blend
#pragma unroll
  for (int i = 0; i < 4; ++i) {
    const int grow0 = bm * 128 + wm + i * 16 + quad * 4;
    float cd_r[4];
    int hb_r[4];
#pragma unroll
    for (int r = 0; r < 4; ++r) {
      const int gr = grow0 + r;
      const int b = gr >> 11;           // gr = b*2048 + s
      const int c = (gr & 2047) >> 7;   // 128-step chunk
      cd_r[r] = cumd[gr];
      hb_r[r] = (b * 16 + c) << 10;
    }
#pragma unroll
    for (int j = 0; j < 4; ++j) {
      const int gcol = bn * 128 + wn + j * 16 + fm;
      const float Ae = Avec[gcol];
      const float bb = bias[gcol];
#pragma unroll
      for (int r = 0; r < 4; ++r) {
        const int gr = grow0 + r;
        const size_t off = (size_t)gr * 1024 + gcol;
        const float hin = chH[hb_r[r] + gcol];
        const float lcl = C[off];
        const float gt  = gate[off];
        float v = acc[i][j][r] + bb;
        v = 0.5f * v * (1.f + erff(v * 0.70710678118654752f));   // exact gelu
        const float p = __expf(Ae * cd_r[r]);                    // prod of A_bar over chunk prefix
        const float sst = lcl + p * hin;                         // true ssm state
        C[off] = v * gt + sst * (1.f - gt);
      }
    }
  }
}

// ---------------- reservoir scan v7: batch-partitioned, 8 groups x 16 WGs x 512 threads ----------------
// KEY: the recurrence is independent PER BATCH. Group go (= batch) of 16 WGs exchanges only its
// own 1024-row h-state via its DISJOINT 4KB slice of each hbuf parity buffer. Protocol per group
// identical to the proven scheme: self-certifying words bf16(h)<<16|tag, relaxed AGENT-scope
// atomics, parity buffers, zeroed before launch.
//   * poll = ONE u64 per thread (its own 2 rows); each thread waits only its own word —
//     the __syncthreads IS the group-arrival rendezvous. 16x less detect traffic than v4.
//   * compute: wave = 8 rows x full K=1024, fp32 W in registers (32x float4 = 128 VGPR,
//     EXACT fp32 x bf16 — better than the bf16 hi/lo split it replaces). Lane l: row l>>3,
//     k-chunk c=l&7; reads ROTATED ((i+c)&31) so the 8 chunk-lanes hit 8 distinct bank
//     groups (broadcast across row groups) — conflict-free; W pre-rotated at load so all
//     register indices are static. 3x shfl_xor reduce over the c lanes.
//   * ONE barrier per step (stage -> barrier -> compute). LDS dbuf reuse: stage(s+2) into
//     hs[s&1] post-dates barrier(s+1), which post-dates every thread's reads(s).
//   * tail: lanes c==0 of a wave store 8 CONSECUTIVE rows -> 32B-contiguous stores (the v5
//     lesson: keep the tail dense).
// Safety (per group): a thread stores tag s+1 only after barrier(s), which post-dates all its
// WG's tag-s polls; a WG overwrites tag-(s+1) words (storing tag s+3 at step s+2) only after
// its poll(s+2) succeeded, certifying every group member stored tag s+2, i.e. passed
// barrier(s+1), i.e. finished all tag-(s+1) polls. Groups are fully decoupled (disjoint hbuf
// slices, disjoint xin rows, private LDS) — free drift, no cross-batch straggler coupling.
// Co-residency: 128 WGs x 8 waves @ <=256 VGPR -> >=1 WG/CU on 256 CUs, all resident.
__global__ __launch_bounds__(512, 2) void reservoir_scan_kernel(
    float* __restrict__ xin_res,       // [8][2048][1024]: in xin, out res states (in-place)
    const float* __restrict__ Wres,    // [1024][1024]
    unsigned* __restrict__ hbuf,       // [2][8][1024] packed words, zeroed before launch
    unsigned* __restrict__ unused)
{
  const int tid = threadIdx.x;
  const int wg  = blockIdx.x;          // 0..127
  const int go  = wg >> 4;             // batch group 0..7
  const int mem = wg & 15;             // member: rows mem*64..mem*64+63
  const int g   = tid >> 6;            // wave 0..7
  const int l   = tid & 63;
  const int c   = l & 7;               // k-chunk (128 k each)
  const int rl  = l >> 3;              // row within wave's 8
  const int row = mem * 64 + g * 8 + rl;   // global hidden row

  __shared__ __align__(16) float hs[2][1024];   // dbuf fp32 h (decoded from bf16 words)

  // ---- W registers: fp32, 8 rows x 1024 K per wave; lane holds its 128-k chunk,
  //      PRE-ROTATED so the compute loop's register index is static. ----
  float4 w4r[32];
  {
    const float* wrow = Wres + (size_t)row * 1024 + c * 128;
#pragma unroll
    for (int i = 0; i < 32; ++i)
      w4r[i] = *(const float4*)(wrow + 4 * ((i + c) & 31));
  }

  float hprev = 0.f;
  const unsigned long long tmask = 0x0000FFFF0000FFFFull;

  for (int s = 0; s < S_; ++s) {
    // ---- prefetch u before the poll (keep-alive pins issue order) ----
    const float u = xin_res[((size_t)go * S_ + s) * H_ + row];
    asm volatile("" :: "v"(u));

    // ---- poll h^s: ONE u64 per thread (rows 2*tid, 2*tid+1 of this group) ----
    const unsigned tag = (unsigned)s & 0xFFFFu;
    const unsigned long long tag2 = (unsigned long long)tag | ((unsigned long long)tag << 32);
    const unsigned long long* hp =
        (const unsigned long long*)(hbuf + (size_t)(s & 1) * 8192 + go * 1024) + tid;
    unsigned long long w;
    for (;;) {
      w = __hip_atomic_load(hp, __ATOMIC_RELAXED, __HIP_MEMORY_SCOPE_AGENT);
      if (((w ^ tag2) & tmask) == 0ull) break;
    }

    // ---- stage as fp32 (mask off tag), one ds_write_b64 ----
    float2 hf;
    hf.x = __uint_as_float((unsigned)w & 0xFFFF0000u);
    hf.y = __uint_as_float((unsigned)(w >> 32) & 0xFFFF0000u);
    *(float2*)(&hs[s & 1][2 * tid]) = hf;
    __syncthreads();                   // the only barrier: staged; all polls done before
                                       // any tag-s+1 store below (safety inv.)

    // ---- fp32 matvec: lane's 128-k chunk, rotated reads (conflict-free, 8-way bcast) ----
    const float* hc = &hs[s & 1][c * 128];
    float p0 = 0.f, p1 = 0.f, p2 = 0.f, p3 = 0.f;
#pragma unroll
    for (int i = 0; i < 32; ++i) {
      const float4 h4 = *(const float4*)(hc + 4 * ((i + c) & 31));
      p0 += w4r[i].x * h4.x;
      p1 += w4r[i].y * h4.y;
      p2 += w4r[i].z * h4.z;
      p3 += w4r[i].w * h4.w;
    }
    float ps = (p0 + p1) + (p2 + p3);
    ps += __shfl_xor(ps, 1);
    ps += __shfl_xor(ps, 2);
    ps += __shfl_xor(ps, 4);           // full dot in all 8 c-lanes of the row group

    // ---- tanh, leak (all lanes; broadcast-consistent), store by c==0 lanes ----
    const float z  = u + ps;
    const float e  = __expf(2.f * z);                 // tanh(z) = 1 - 2/(e^{2z}+1)
    const float hn = 1.f - __fdividef(2.f, e + 1.f);  // saturates correctly
    const float hv = 0.95f * hn + 0.05f * hprev;
    hprev = hv;

    if (c == 0) {
      const unsigned word = ((__float_as_uint(hv) + 0x8000u) & 0xFFFF0000u)
                          | ((unsigned)(s + 1) & 0xFFFFu);
      __hip_atomic_store(hbuf + (size_t)((s + 1) & 1) * 8192 + go * 1024 + row, word,
                         __ATOMIC_RELAXED, __HIP_MEMORY_SCOPE_AGENT);
      xin_res[((size_t)go * S_ + s) * H_ + row] = hv;  // fp32 states, 32B-dense per wave
    }
    // no drain, no flag, no rendezvous — next iteration's poll is the wait
  }
}

// ---------------- SSM chunked scan ----------------
// within-chunk cumulative delta (tiny)
__global__ __launch_bounds__(128) void cumd_kernel(
    const float* __restrict__ delta, float* __restrict__ cumd)
{
  const int t = threadIdx.x;          // 128 = 8 batches * 16 chunks
  const int b = t >> 4, c = t & 15;
  const int base = b * S_ + c * 128;
  float acc = 0.f;
  for (int i = 0; i < 128; ++i) { acc += delta[base + i]; cumd[base + i] = acc; }
}

// phase A: per-chunk local scan, in-place Bx -> local states; store chunk products
__global__ __launch_bounds__(256) void ssm_partial_kernel(
    const float* __restrict__ delta, const float* __restrict__ Avec,
    float* __restrict__ bx, float* __restrict__ P)
{
  const int idx = blockIdx.x * 256 + threadIdx.x;
  const int h = idx & 1023;
  const int c = (idx >> 10) & 15;
  const int b = idx >> 14;
  const float Ah = Avec[h];
  const float inv = 1.f / (Ah + 1e-8f);
  const float* dp = delta + b * S_ + c * 128;
  float* xp = bx + ((size_t)(b * S_ + c * 128)) * H_ + h;
  float p = 1.f, hl = 0.f;
  for (int t = 0; t < 128; ++t) {
    const float a = __expf(Ah * dp[t]);
    const float bb = xp[(size_t)t * H_] * (1.f - a) * inv;
    hl = a * hl + bb;
    p *= a;
    xp[(size_t)t * H_] = hl;
  }
  P[(b * 16 + c) * 1024 + h] = p;
}

// phase B: sequential combine over 16 chunks -> per-chunk initial states
__global__ __launch_bounds__(256) void ssm_combine_kernel(
    const float* __restrict__ P, const float* __restrict__ local, float* __restrict__ Hin)
{
  const int idx = blockIdx.x * 256 + threadIdx.x;  // 8192
  const int h = idx & 1023;
  const int b = idx >> 10;
  float hh = 0.f;
#pragma unroll
  for (int c = 0; c < 16; ++c) {
    const int o = (b * 16 + c) * 1024 + h;
    Hin[o] = hh;
    hh = P[o] * hh + local[((size_t)(b * S_ + c * 128 + 127)) * H_ + h];
  }
}

// ---------------- host launch ----------------
extern "C" void kernel_launch(void* const* d_in, const int* in_sizes, int n_in,
                              void* d_out, int out_size, void* d_ws, size_t ws_size,
                              hipStream_t stream) {
  (void)in_sizes; (void)n_in; (void)out_size; (void)ws_size;
  const float* x      = (const float*)d_in[0];
  const float* W_in   = (const float*)d_in[1];
  const float* W_res  = (const float*)d_in[2];
  const float* norm_g = (const float*)d_in[3];
  const float* norm_b = (const float*)d_in[4];
  const float* dw     = (const float*)d_in[5];
  const float* db     = (const float*)d_in[6];
  const float* Avec   = (const float*)d_in[7];
  const float* B_w    = (const float*)d_in[8];
  const float* ro_g   = (const float*)d_in[9];
  const float* ro_b   = (const float*)d_in[10];
  const float* ro_w   = (const float*)d_in[11];
  const float* ro_bias= (const float*)d_in[12];
  const float* gate_w = (const float*)d_in[13];
  const float* gate_b = (const float*)d_in[14];
  float* out = (float*)d_out;
  float* ws  = (float*)d_ws;

  float*    buf0   = ws;                    // bf16 x_norm (first 32MB), later fp32 gate (64MB)
  float*    buf1   = ws + 16777216;         // xin -> reservoir states (in-place)
  float*    delta  = ws + 33554432;         // [M]
  float*    cumd   = ws + 33570816;         // [M]
  unsigned* hbuf   = (unsigned*)(ws + 33587200);  // [2][8][1024] packed words
  float2*   stats  = (float2*)(ws + 33603712);
  float*    chP    = ws + 33636480;         // [B,16,1024]
  float*    chH    = ws + 33767552;         // [B,16,1024]
  unsigned short* xnb = (unsigned short*)buf0;            // bf16 x_norm [M,1024]
  unsigned short* wib = (unsigned short*)(ws + 33898624); // bf16 W_in   [1024,1024]
  unsigned short* bwb = (unsigned short*)(ws + 34422912); // bf16 B_w
  unsigned short* roh = (unsigned short*)(ws + 34947200); // bf16 hi(ro_w)
  unsigned short* rol = (unsigned short*)(ws + 35471488); // bf16 lo(ro_w)

  // 0. weight conversions (once per launch, tiny)
  tobf16_kernel<<<1024, 256, 0, stream>>>(W_in, wib);
  tobf16_kernel<<<1024, 256, 0, stream>>>(B_w, bwb);
  splitw_kernel<<<1024, 256, 0, stream>>>(ro_w, roh, rol);
  // 1. layernorm -> bf16 x_norm + delta
  ln_delta_kernel<<<M_, 256, 0, stream>>>(x, norm_g, norm_b, dw, db, xnb, delta);
  // 2. xin = x_norm @ W_in^T   -> buf1   (bf16 x bf16 MFMA)
  gemm_bb<<<1024, 256, 0, stream>>>(xnb, wib, buf1);
  // 3. Bx = x_norm @ B_w^T     -> d_out (scratch)
  gemm_bb<<<1024, 256, 0, stream>>>(xnb, bwb, out);
  // 4. gate = sigmoid(x @ gate_w^T + gate_b) -> buf0 (xnb dead)   (fp32-input path)
  gemm_bf16_nt<1><<<1024, 256, 0, stream>>>(x, gate_w, gate_b, buf0);
  // 5. ssm chunked scan pieces (independent of reservoir)
  cumd_kernel<<<1, 128, 0, stream>>>(delta, cumd);
  ssm_partial_kernel<<<512, 256, 0, stream>>>(delta, Avec, out, chP);
  ssm_combine_kernel<<<32, 256, 0, stream>>>(chP, out, chH);
  // 6. reservoir scan (zero both parity buffers: word 0 == tag 0 | bf16(0))
  hipMemsetAsync(hbuf, 0, 2 * 8192 * sizeof(unsigned), stream);
  reservoir_scan_kernel<<<128, 512, 0, stream>>>(buf1, W_res, hbuf, nullptr);
  // 7. ro-layernorm stats
  rowstats_kernel<<<M_, 256, 0, stream>>>(buf1, stats);
  // 8. readout GEMM (MFMA hi/lo, pre-split W) + gelu + ssm recon + gate blend -> d_out
  gemm_readout_mfma<<<1024, 256, 0, stream>>>(buf1, roh, rol, ro_bias, stats, ro_g, ro_b,
                                              Avec, cumd, chH, buf0, out);
}